// Round 1
// baseline (290.226 us; speedup 1.0000x reference)
//
#include <hip/hip_runtime.h>
#include <cstdint>

typedef unsigned short u16;

#define NTOK 2048
#define DMODEL 1024
#define NHEAD 16
#define HDIM 64
#define NOFF 44

__constant__ int c_offs[NOFF] = {
    0,1,2,3,4,5,6,7,8,9,10,11,12,13,14,15,16,17,18,19,20,21,22,23,24,25,26,
    27,28,29,30,31,32,48,64,96,128,192,256,384,512,768,1024,1536};

typedef __attribute__((ext_vector_type(8))) short bf16x8;
typedef __attribute__((ext_vector_type(4))) float f32x4;

__device__ __forceinline__ u16 f2bf(float f) {
  uint32_t u = __builtin_bit_cast(uint32_t, f);
  u = (u + 0x7FFFu + ((u >> 16) & 1u)) >> 16;
  return (u16)u;
}
__device__ __forceinline__ float bf2f(u16 u) {
  return __builtin_bit_cast(float, ((uint32_t)u) << 16);
}

// ---------------- fp32 -> bf16 convert (vectorized x4) ----------------
__global__ __launch_bounds__(256) void cvt_bf16_kernel(
    const float* __restrict__ in, u16* __restrict__ out, int n4) {
  int i = blockIdx.x * blockDim.x + threadIdx.x;
  if (i >= n4) return;
  float4 f = reinterpret_cast<const float4*>(in)[i];
  ushort4 o;
  o.x = f2bf(f.x); o.y = f2bf(f.y); o.z = f2bf(f.z); o.w = f2bf(f.w);
  reinterpret_cast<ushort4*>(out)[i] = o;
}

// ---------------- async global->LDS 16B ----------------
__device__ __forceinline__ void async16(const void* g, void* l) {
  __builtin_amdgcn_global_load_lds(
      (const __attribute__((address_space(1))) void*)g,
      (__attribute__((address_space(3))) void*)l,
      16, 0, 0);
}

// ---------------- bf16 MFMA GEMM: C = A @ B^T + bias ----------------
// A: [M,K] bf16 row-major, B: [Nout,K] bf16 row-major (i.e. W, contraction
// over last dim of both). 128x128 tile, BK=32, 256 threads = 4 waves (2x2),
// each wave 64x64 via 4x4 mfma_f32_16x16x32_bf16.
// MODE 0: out bf16 (u16*), +bias          (qkv)
// MODE 1: out fp32, sigmoid(x+bias)       (gate)
// MODE 2: out fp32, +bias                 (final)
template <int MODE>
__global__ __launch_bounds__(256) void gemm_bt(
    const u16* __restrict__ A, const u16* __restrict__ B,
    const float* __restrict__ bias, void* __restrict__ Cv,
    int M, int Nout, int K) {
  __shared__ __align__(16) u16 As[128 * 32];
  __shared__ __align__(16) u16 Bs[128 * 32];
  const int tid = threadIdx.x;
  const int lane = tid & 63;
  const int w = tid >> 6;            // wave 0..3
  const int wm = w >> 1, wn = w & 1; // 2x2 wave grid
  const int tile_m = blockIdx.y * 128;
  const int tile_n = blockIdx.x * 128;

  f32x4 acc[4][4];
  const f32x4 zero = {0.f, 0.f, 0.f, 0.f};
#pragma unroll
  for (int mi = 0; mi < 4; ++mi)
#pragma unroll
    for (int ni = 0; ni < 4; ++ni) acc[mi][ni] = zero;

  const int rowInChunk = lane >> 2;      // 0..15
  const int colChunk = (lane & 3) * 8;   // 0,8,16,24 elements

  for (int k0 = 0; k0 < K; k0 += 32) {
#pragma unroll
    for (int j = 0; j < 2; ++j) {
      int r = w * 32 + j * 16 + rowInChunk;     // 0..127
      const u16* gA = A + (size_t)(tile_m + r) * K + k0 + colChunk;
      async16(gA, As + r * 32 + colChunk);
      const u16* gB = B + (size_t)(tile_n + r) * K + k0 + colChunk;
      async16(gB, Bs + r * 32 + colChunk);
    }
    __syncthreads();

    bf16x8 af[4], bfr[4];
#pragma unroll
    for (int mi = 0; mi < 4; ++mi)
      af[mi] = *(const bf16x8*)(As + (wm * 64 + mi * 16 + (lane & 15)) * 32 +
                                (lane >> 4) * 8);
#pragma unroll
    for (int ni = 0; ni < 4; ++ni)
      bfr[ni] = *(const bf16x8*)(Bs + (wn * 64 + ni * 16 + (lane & 15)) * 32 +
                                 (lane >> 4) * 8);
#pragma unroll
    for (int mi = 0; mi < 4; ++mi)
#pragma unroll
      for (int ni = 0; ni < 4; ++ni)
        acc[mi][ni] = __builtin_amdgcn_mfma_f32_16x16x32_bf16(
            af[mi], bfr[ni], acc[mi][ni], 0, 0, 0);
    __syncthreads();
  }

  // epilogue: C row = tile_m + wm*64 + mi*16 + (lane>>4)*4 + r
  //           C col = tile_n + wn*64 + ni*16 + (lane&15)
  const int r0 = tile_m + wm * 64 + ((lane >> 4) << 2);
  const int c0 = tile_n + wn * 64 + (lane & 15);
#pragma unroll
  for (int mi = 0; mi < 4; ++mi) {
#pragma unroll
    for (int ni = 0; ni < 4; ++ni) {
      int col = c0 + ni * 16;
      float bv = bias[col];
#pragma unroll
      for (int r = 0; r < 4; ++r) {
        float val = acc[mi][ni][r] + bv;
        size_t idx = (size_t)(r0 + mi * 16 + r) * Nout + col;
        if (MODE == 0) {
          ((u16*)Cv)[idx] = f2bf(val);
        } else if (MODE == 1) {
          ((float*)Cv)[idx] = 1.f / (1.f + __expf(-val));
        } else {
          ((float*)Cv)[idx] = val;
        }
      }
    }
  }
}

// ---------------- attention: one wave per (h, n), online softmax ----------
// qkv: [N, 3072] bf16 (q|k|v each 1024 = 16 heads x 64)
// writes a2[n, h*64+d] = bf16( attn_out * gate )
__global__ __launch_bounds__(256) void attn_kernel(
    const u16* __restrict__ qkv, const float* __restrict__ pos_bias,
    const float* __restrict__ gate, u16* __restrict__ a2) {
  const int lane = threadIdx.x & 63;
  const int wid = blockIdx.x * 4 + (threadIdx.x >> 6); // 0..32767
  const int n = wid & (NTOK - 1);
  const int h = wid >> 11;

  const u16* qrow = qkv + (size_t)n * 3072 + h * 64;
  const u16* kcol = qkv + 1024 + h * 64 + lane;
  const u16* vcol = qkv + 2048 + h * 64 + lane;

  float qd = bf2f(qrow[lane]) * 0.125f; // scale = 64^-0.5 folded into q
  float m = -INFINITY, l = 0.f, acc = 0.f;

  for (int o = 0; o < NOFF; ++o) {
    int src = n - c_offs[o];
    if (src < 0) break; // offsets ascending; later ones also invalid
    float s = qd * bf2f(kcol[src * 3072]);
    s += __shfl_xor(s, 32, 64);
    s += __shfl_xor(s, 16, 64);
    s += __shfl_xor(s, 8, 64);
    s += __shfl_xor(s, 4, 64);
    s += __shfl_xor(s, 2, 64);
    s += __shfl_xor(s, 1, 64);
    s += pos_bias[o * NHEAD + h];
    float mn = fmaxf(m, s);
    float cold = __expf(m - mn); // exp(-inf)=0 on first iter
    float p = __expf(s - mn);
    l = l * cold + p;
    acc = acc * cold + p * bf2f(vcol[src * 3072]);
    m = mn;
  }

  float outd = acc / l;
  int j = h * 64 + lane;
  float g = gate[(size_t)n * DMODEL + j];
  a2[(size_t)n * DMODEL + j] = f2bf(outd * g);
}

extern "C" void kernel_launch(void* const* d_in, const int* in_sizes, int n_in,
                              void* d_out, int out_size, void* d_ws,
                              size_t ws_size, hipStream_t stream) {
  (void)in_sizes; (void)n_in; (void)out_size; (void)ws_size;
  const float* x = (const float*)d_in[0];
  const float* Wqkv = (const float*)d_in[1];
  const float* bqkv = (const float*)d_in[2];
  const float* Wout = (const float*)d_in[3];
  const float* bout = (const float*)d_in[4];
  const float* Wgate = (const float*)d_in[5];
  const float* bgate = (const float*)d_in[6];
  const float* pos_bias = (const float*)d_in[7];
  float* out = (float*)d_out;

  char* ws = (char*)d_ws;
  u16* xb     = (u16*)(ws);                       // 2048*1024*2   = 4 MB
  u16* Wqkvb  = (u16*)(ws + (4u << 20));          // 3072*1024*2   = 6 MB
  u16* Wgateb = (u16*)(ws + (10u << 20));         // 1024*1024*2   = 2 MB
  u16* Woutb  = (u16*)(ws + (12u << 20));         // 1024*1024*2   = 2 MB
  u16* qkvb   = (u16*)(ws + (14u << 20));         // 2048*3072*2   = 12 MB
  float* gate = (float*)(ws + (26u << 20));       // 2048*1024*4   = 8 MB
  u16* a2     = (u16*)(ws + (34u << 20));         // 2048*1024*2   = 4 MB

  cvt_bf16_kernel<<<2048, 256, 0, stream>>>(x, xb, 524288);
  cvt_bf16_kernel<<<3072, 256, 0, stream>>>(Wqkv, Wqkvb, 786432);
  cvt_bf16_kernel<<<1024, 256, 0, stream>>>(Wgate, Wgateb, 262144);
  cvt_bf16_kernel<<<1024, 256, 0, stream>>>(Wout, Woutb, 262144);

  // qkv = x @ Wqkv^T + bqkv   -> bf16 [2048, 3072]
  gemm_bt<0><<<dim3(24, 16), 256, 0, stream>>>(xb, Wqkvb, bqkv, qkvb,
                                               2048, 3072, 1024);
  // gate = sigmoid(x @ Wgate^T + bgate) -> fp32 [2048, 1024]
  gemm_bt<1><<<dim3(8, 16), 256, 0, stream>>>(xb, Wgateb, bgate, gate,
                                              2048, 1024, 1024);
  // attention + gating -> a2 bf16 [2048, 1024]
  attn_kernel<<<8192, 256, 0, stream>>>(qkvb, pos_bias, gate, a2);
  // out = a2 @ Wout^T + bout -> fp32 [2048, 1024]
  gemm_bt<2><<<dim3(8, 16), 256, 0, stream>>>(a2, Woutb, bout, out,
                                              2048, 1024, 1024);
}

// Round 2
// 173.945 us; speedup vs baseline: 1.6685x; 1.6685x over previous
//
#include <hip/hip_runtime.h>
#include <cstdint>

typedef unsigned short u16;

#define NTOK 2048
#define DMODEL 1024
#define NHEAD 16
#define NOFF 44

typedef __attribute__((ext_vector_type(8))) short bf16x8;
typedef __attribute__((ext_vector_type(4))) float f32x4;

__device__ __forceinline__ u16 f2bf(float f) {
  uint32_t u = __builtin_bit_cast(uint32_t, f);
  u = (u + 0x7FFFu + ((u >> 16) & 1u)) >> 16;
  return (u16)u;
}

// ---------------- merged fp32 -> bf16 convert ----------------
__global__ __launch_bounds__(256) void cvt_all_kernel(
    const float* __restrict__ x, const float* __restrict__ wq,
    const float* __restrict__ wg, const float* __restrict__ wo,
    u16* __restrict__ xb, u16* __restrict__ wqb,
    u16* __restrict__ wgb, u16* __restrict__ wob) {
  int i = blockIdx.x * 256 + threadIdx.x;
  const float* in; u16* out; int off;
  if (i < 524288) { in = x; out = xb; off = 0; }
  else if (i < 524288 + 786432) { in = wq; out = wqb; off = 524288; }
  else if (i < 524288 + 786432 + 262144) { in = wg; out = wgb; off = 524288 + 786432; }
  else { in = wo; out = wob; off = 524288 + 786432 + 262144; }
  int j = i - off;
  float4 f = reinterpret_cast<const float4*>(in)[j];
  ushort4 o;
  o.x = f2bf(f.x); o.y = f2bf(f.y); o.z = f2bf(f.z); o.w = f2bf(f.w);
  reinterpret_cast<ushort4*>(out)[j] = o;
}

// ---------------- async global->LDS 16B ----------------
__device__ __forceinline__ void async16(const void* g, void* l) {
  __builtin_amdgcn_global_load_lds(
      (const __attribute__((address_space(1))) void*)g,
      (__attribute__((address_space(3))) void*)l,
      16, 0, 0);
}

// ---------------- bf16 MFMA GEMM: C = A @ B^T + bias ----------------
// BN=128: 128x128 tile, 4 waves 2x2, each 64x64 (acc 4x4)
// BN=64 : 128x64  tile, 4 waves 4x1, each 32x64 (acc 2x4) -> 2x blocks
template <int MODE, int BN>
__global__ __launch_bounds__(256) void gemm_bt(
    const u16* __restrict__ A, const u16* __restrict__ B,
    const float* __restrict__ bias, void* __restrict__ Cv,
    int M, int Nout, int K) {
  constexpr int MI = (BN == 128) ? 4 : 2;
  __shared__ __align__(16) u16 As[128 * 32];
  __shared__ __align__(16) u16 Bs[BN * 32];
  const int tid = threadIdx.x;
  const int lane = tid & 63;
  const int w = tid >> 6;
  const int wm = (BN == 128) ? (w >> 1) : w;
  const int wn = (BN == 128) ? (w & 1) : 0;
  const int wrow0 = wm * (MI * 16);
  const int tile_m = blockIdx.y * 128;
  const int tile_n = blockIdx.x * BN;
  const int l15 = lane & 15;
  const int quad = lane >> 4;

  f32x4 acc[MI][4];
  const f32x4 zero = {0.f, 0.f, 0.f, 0.f};
#pragma unroll
  for (int mi = 0; mi < MI; ++mi)
#pragma unroll
    for (int ni = 0; ni < 4; ++ni) acc[mi][ni] = zero;

  const int rowInChunk = lane >> 2;
  const int colChunk = (lane & 3) * 8;

  for (int k0 = 0; k0 < K; k0 += 32) {
#pragma unroll
    for (int j = 0; j < 2; ++j) {
      int r = w * 32 + j * 16 + rowInChunk;
      async16(A + (size_t)(tile_m + r) * K + k0 + colChunk, As + r * 32 + colChunk);
    }
    if constexpr (BN == 128) {
#pragma unroll
      for (int j = 0; j < 2; ++j) {
        int r = w * 32 + j * 16 + rowInChunk;
        async16(B + (size_t)(tile_n + r) * K + k0 + colChunk, Bs + r * 32 + colChunk);
      }
    } else {
      int r = tid >> 2;
      int cc = (tid & 3) * 8;
      async16(B + (size_t)(tile_n + r) * K + k0 + cc, Bs + r * 32 + cc);
    }
    __syncthreads();

    bf16x8 af[MI], bfr[4];
#pragma unroll
    for (int mi = 0; mi < MI; ++mi)
      af[mi] = *(const bf16x8*)(As + (wrow0 + mi * 16 + l15) * 32 + quad * 8);
#pragma unroll
    for (int ni = 0; ni < 4; ++ni)
      bfr[ni] = *(const bf16x8*)(Bs + (wn * 64 + ni * 16 + l15) * 32 + quad * 8);
#pragma unroll
    for (int mi = 0; mi < MI; ++mi)
#pragma unroll
      for (int ni = 0; ni < 4; ++ni)
        acc[mi][ni] = __builtin_amdgcn_mfma_f32_16x16x32_bf16(
            af[mi], bfr[ni], acc[mi][ni], 0, 0, 0);
    __syncthreads();
  }

  const int r0 = tile_m + wrow0 + quad * 4;
  const int c0 = tile_n + wn * 64 + l15;
#pragma unroll
  for (int mi = 0; mi < MI; ++mi) {
#pragma unroll
    for (int ni = 0; ni < 4; ++ni) {
      int col = c0 + ni * 16;
      float bv = bias[col];
#pragma unroll
      for (int r = 0; r < 4; ++r) {
        float val = acc[mi][ni][r] + bv;
        size_t idx = (size_t)(r0 + mi * 16 + r) * Nout + col;
        if (MODE == 0) {
          ((u16*)Cv)[idx] = f2bf(val);
        } else if (MODE == 1) {
          ((float*)Cv)[idx] = 1.f / (1.f + __expf(-val));
        } else {
          ((float*)Cv)[idx] = val;
        }
      }
    }
  }
}

// ---------------- MFMA attention ----------------
// Block = (head, 64 queries), 4 waves x 16 queries. Per wave:
// 14 key-groups of 16 rows: g0..2 dense (bases n0-32,n0-16,n0) cover o=0..32;
// g3..13 sparse offsets (diagonal-only, off-diag masked to exp(-inf)=0).
// QK: 28 MFMAs (B-frags straight from global K rows).
// softmax: in-register, 4-step intra-quad butterfly over 224-wide rows.
// P: C-layout -> LDS bf16 [q][232] -> A-layout b128 reads.
// PV: 28 MFMAs, B-frags = V^T scalar gathers (L1/L2-hot window).
__global__ __launch_bounds__(256) void attn_mfma_kernel(
    const u16* __restrict__ qkv, const float* __restrict__ pos_bias,
    const float* __restrict__ gate, u16* __restrict__ a2) {
  __shared__ __align__(16) u16 Pl[4][16][232];
  __shared__ float pbs[NOFF];
  const int tid = threadIdx.x;
  const int lane = tid & 63;
  const int w = tid >> 6;
  const int h = blockIdx.y;
  const int n0 = blockIdx.x * 64 + w * 16;
  const int quad = lane >> 4;
  const int l15 = lane & 15;

  if (tid < NOFF) pbs[tid] = pos_bias[tid * NHEAD + h];

  const int soffs[11] = {48, 64, 96, 128, 192, 256, 384, 512, 768, 1024, 1536};
  int gbase[14];
  gbase[0] = n0 - 32; gbase[1] = n0 - 16; gbase[2] = n0;
#pragma unroll
  for (int g = 0; g < 11; ++g) gbase[3 + g] = n0 - soffs[g];

  // Q A-frags
  const u16* qbase = qkv + (size_t)(n0 + l15) * 3072 + h * 64 + quad * 8;
  bf16x8 aq0 = *(const bf16x8*)(qbase);
  bf16x8 aq1 = *(const bf16x8*)(qbase + 32);

  // QK^T
  f32x4 s[14];
  const f32x4 zero = {0.f, 0.f, 0.f, 0.f};
#pragma unroll
  for (int g = 0; g < 14; ++g) {
    s[g] = zero;
    if (gbase[g] + 15 < 0) continue;  // wave-uniform: whole group invalid
    int row = gbase[g] + l15;
    int rc = row < 0 ? 0 : row;
    const u16* kb = qkv + 1024 + (size_t)rc * 3072 + h * 64 + quad * 8;
    bf16x8 bk0 = *(const bf16x8*)(kb);
    bf16x8 bk1 = *(const bf16x8*)(kb + 32);
    s[g] = __builtin_amdgcn_mfma_f32_16x16x32_bf16(aq0, bk0, s[g], 0, 0, 0);
    s[g] = __builtin_amdgcn_mfma_f32_16x16x32_bf16(aq1, bk1, s[g], 0, 0, 0);
  }
  __syncthreads();  // pbs ready

  // scale + bias + mask
#pragma unroll
  for (int g = 0; g < 14; ++g) {
    int key = gbase[g] + l15;
#pragma unroll
    for (int r = 0; r < 4; ++r) {
      int q = n0 + quad * 4 + r;
      int o = q - key;
      bool valid; int bidx;
      if (g < 3) {
        valid = (o >= 0) & (o <= 32) & (key >= 0);
        bidx = o < 0 ? 0 : (o > 32 ? 32 : o);
      } else {
        valid = (key >= 0) & (o == soffs[g - 3]);
        bidx = g + 30;  // 33 + (g-3)
      }
      float val = s[g][r] * 0.125f + pbs[bidx];
      s[g][r] = valid ? val : -INFINITY;
    }
  }

  // softmax over 224-wide rows (14 regs x 16 lanes per quad)
  float rl[4];
#pragma unroll
  for (int r = 0; r < 4; ++r) {
    float mx = s[0][r];
#pragma unroll
    for (int g = 1; g < 14; ++g) mx = fmaxf(mx, s[g][r]);
    mx = fmaxf(mx, __shfl_xor(mx, 1, 64));
    mx = fmaxf(mx, __shfl_xor(mx, 2, 64));
    mx = fmaxf(mx, __shfl_xor(mx, 4, 64));
    mx = fmaxf(mx, __shfl_xor(mx, 8, 64));
    float sum = 0.f;
#pragma unroll
    for (int g = 0; g < 14; ++g) {
      float p = __expf(s[g][r] - mx);
      s[g][r] = p;
      sum += p;
    }
    sum += __shfl_xor(sum, 1, 64);
    sum += __shfl_xor(sum, 2, 64);
    sum += __shfl_xor(sum, 4, 64);
    sum += __shfl_xor(sum, 8, 64);
    rl[r] = 1.0f / sum;
  }

  // P -> LDS (C-layout write, A-layout read)
#pragma unroll
  for (int g = 0; g < 14; ++g)
#pragma unroll
    for (int r = 0; r < 4; ++r)
      Pl[w][quad * 4 + r][g * 16 + l15] = f2bf(s[g][r]);
  __syncthreads();

  // PV: out[16][64] = P[16][224] @ V_sel[224][64]
  f32x4 ov[4];
#pragma unroll
  for (int ni = 0; ni < 4; ++ni) ov[ni] = zero;
  const u16* vb = qkv + 2048 + h * 64;
#pragma unroll
  for (int kc = 0; kc < 7; ++kc) {
    if (gbase[2 * kc] + 15 < 0 && gbase[2 * kc + 1] + 15 < 0) continue;
    bf16x8 ap = *(const bf16x8*)(&Pl[w][l15][kc * 32 + quad * 8]);
    int g = kc * 2 + (quad >> 1);
    int keyg = gbase[g] + (quad & 1) * 8;
    const u16* rp[8];
#pragma unroll
    for (int j = 0; j < 8; ++j) {
      int row = keyg + j;
      rp[j] = vb + (size_t)(row < 0 ? 0 : row) * 3072;
    }
#pragma unroll
    for (int ni = 0; ni < 4; ++ni) {
      bf16x8 bv;
#pragma unroll
      for (int j = 0; j < 8; ++j) bv[j] = (short)rp[j][ni * 16 + l15];
      ov[ni] = __builtin_amdgcn_mfma_f32_16x16x32_bf16(ap, bv, ov[ni], 0, 0, 0);
    }
  }

  // epilogue: normalize, gate, store bf16
#pragma unroll
  for (int ni = 0; ni < 4; ++ni) {
#pragma unroll
    for (int r = 0; r < 4; ++r) {
      int q = n0 + quad * 4 + r;
      int col = h * 64 + ni * 16 + l15;
      float o = ov[ni][r] * rl[r];
      float g = gate[(size_t)q * DMODEL + col];
      a2[(size_t)q * DMODEL + col] = f2bf(o * g);
    }
  }
}

extern "C" void kernel_launch(void* const* d_in, const int* in_sizes, int n_in,
                              void* d_out, int out_size, void* d_ws,
                              size_t ws_size, hipStream_t stream) {
  (void)in_sizes; (void)n_in; (void)out_size; (void)ws_size;
  const float* x = (const float*)d_in[0];
  const float* Wqkv = (const float*)d_in[1];
  const float* bqkv = (const float*)d_in[2];
  const float* Wout = (const float*)d_in[3];
  const float* bout = (const float*)d_in[4];
  const float* Wgate = (const float*)d_in[5];
  const float* bgate = (const float*)d_in[6];
  const float* pos_bias = (const float*)d_in[7];
  float* out = (float*)d_out;

  char* ws = (char*)d_ws;
  u16* xb     = (u16*)(ws);
  u16* Wqkvb  = (u16*)(ws + (4u << 20));
  u16* Wgateb = (u16*)(ws + (10u << 20));
  u16* Woutb  = (u16*)(ws + (12u << 20));
  u16* qkvb   = (u16*)(ws + (14u << 20));
  float* gate = (float*)(ws + (26u << 20));
  u16* a2     = (u16*)(ws + (34u << 20));

  cvt_all_kernel<<<7168, 256, 0, stream>>>(x, Wqkv, Wgate, Wout,
                                           xb, Wqkvb, Wgateb, Woutb);

  // qkv = x @ Wqkv^T + bqkv -> bf16 [2048, 3072]
  gemm_bt<0, 128><<<dim3(24, 16), 256, 0, stream>>>(xb, Wqkvb, bqkv, qkvb,
                                                    2048, 3072, 1024);
  // gate = sigmoid(x @ Wgate^T + bgate) -> fp32 [2048, 1024]
  gemm_bt<1, 64><<<dim3(16, 16), 256, 0, stream>>>(xb, Wgateb, bgate, gate,
                                                   2048, 1024, 1024);
  // attention + gating -> a2 bf16 [2048, 1024]
  attn_mfma_kernel<<<dim3(32, 16), 256, 0, stream>>>(qkvb, pos_bias, gate, a2);
  // out = a2 @ Wout^T + bout -> fp32 [2048, 1024]
  gemm_bt<2, 64><<<dim3(16, 16), 256, 0, stream>>>(a2, Woutb, bout, out,
                                                   2048, 1024, 1024);
}

// Round 3
// 157.386 us; speedup vs baseline: 1.8440x; 1.1052x over previous
//
#include <hip/hip_runtime.h>
#include <cstdint>

typedef unsigned short u16;

#define NTOK 2048
#define DMODEL 1024
#define NHEAD 16
#define NOFF 44

typedef __attribute__((ext_vector_type(8))) short bf16x8;
typedef __attribute__((ext_vector_type(4))) float f32x4;

__device__ __forceinline__ u16 f2bf(float f) {
  uint32_t u = __builtin_bit_cast(uint32_t, f);
  u = (u + 0x7FFFu + ((u >> 16) & 1u)) >> 16;
  return (u16)u;
}
__device__ __forceinline__ float bf2f(u16 u) {
  return __builtin_bit_cast(float, ((uint32_t)u) << 16);
}

// ---------------- merged fp32 -> bf16 convert ----------------
__global__ __launch_bounds__(256) void cvt_all_kernel(
    const float* __restrict__ x, const float* __restrict__ wq,
    const float* __restrict__ wg, const float* __restrict__ wo,
    u16* __restrict__ xb, u16* __restrict__ wqb,
    u16* __restrict__ wgb, u16* __restrict__ wob) {
  int i = blockIdx.x * 256 + threadIdx.x;
  const float* in; u16* out; int off;
  if (i < 524288) { in = x; out = xb; off = 0; }
  else if (i < 524288 + 786432) { in = wq; out = wqb; off = 524288; }
  else if (i < 524288 + 786432 + 262144) { in = wg; out = wgb; off = 524288 + 786432; }
  else { in = wo; out = wob; off = 524288 + 786432 + 262144; }
  int j = i - off;
  float4 f = reinterpret_cast<const float4*>(in)[j];
  ushort4 o;
  o.x = f2bf(f.x); o.y = f2bf(f.y); o.z = f2bf(f.z); o.w = f2bf(f.w);
  reinterpret_cast<ushort4*>(out)[j] = o;
}

// ---------------- async global->LDS 16B ----------------
__device__ __forceinline__ void async16(const void* g, void* l) {
  __builtin_amdgcn_global_load_lds(
      (const __attribute__((address_space(1))) void*)g,
      (__attribute__((address_space(3))) void*)l,
      16, 0, 0);
}

// ---------------- bf16 MFMA GEMM: C = A @ B^T + bias ----------------
// BN=128: 128x128 tile, 4 waves 2x2, each 64x64 (acc 4x4)
// BN=64 : 128x64  tile, 4 waves 4x1, each 32x64 (acc 2x4)
// MODE 0: fused qkv+gate — cols [0,3072) -> bf16 qkv (+bias), cols
//         [3072,4096) -> bf16 sigmoid gate (+bias2). Region block-uniform.
// MODE 2: fp32 out (+bias)
template <int MODE, int BN>
__global__ __launch_bounds__(256) void gemm_bt(
    const u16* __restrict__ A, const u16* __restrict__ B,
    const float* __restrict__ bias, void* __restrict__ Cv,
    u16* __restrict__ C2, const float* __restrict__ bias2,
    int M, int Nout, int K) {
  constexpr int MI = (BN == 128) ? 4 : 2;
  __shared__ __align__(16) u16 As[128 * 32];
  __shared__ __align__(16) u16 Bs[BN * 32];
  const int tid = threadIdx.x;
  const int lane = tid & 63;
  const int w = tid >> 6;
  const int wm = (BN == 128) ? (w >> 1) : w;
  const int wn = (BN == 128) ? (w & 1) : 0;
  const int wrow0 = wm * (MI * 16);
  const int tile_m = blockIdx.y * 128;
  const int tile_n = blockIdx.x * BN;
  const int l15 = lane & 15;
  const int quad = lane >> 4;

  f32x4 acc[MI][4];
  const f32x4 zero = {0.f, 0.f, 0.f, 0.f};
#pragma unroll
  for (int mi = 0; mi < MI; ++mi)
#pragma unroll
    for (int ni = 0; ni < 4; ++ni) acc[mi][ni] = zero;

  const int rowInChunk = lane >> 2;
  const int colChunk = (lane & 3) * 8;

  for (int k0 = 0; k0 < K; k0 += 32) {
#pragma unroll
    for (int j = 0; j < 2; ++j) {
      int r = w * 32 + j * 16 + rowInChunk;
      async16(A + (size_t)(tile_m + r) * K + k0 + colChunk, As + r * 32 + colChunk);
    }
    if constexpr (BN == 128) {
#pragma unroll
      for (int j = 0; j < 2; ++j) {
        int r = w * 32 + j * 16 + rowInChunk;
        async16(B + (size_t)(tile_n + r) * K + k0 + colChunk, Bs + r * 32 + colChunk);
      }
    } else {
      int r = tid >> 2;
      int cc = (tid & 3) * 8;
      async16(B + (size_t)(tile_n + r) * K + k0 + cc, Bs + r * 32 + cc);
    }
    __syncthreads();

    bf16x8 af[MI], bfr[4];
#pragma unroll
    for (int mi = 0; mi < MI; ++mi)
      af[mi] = *(const bf16x8*)(As + (wrow0 + mi * 16 + l15) * 32 + quad * 8);
#pragma unroll
    for (int ni = 0; ni < 4; ++ni)
      bfr[ni] = *(const bf16x8*)(Bs + (wn * 64 + ni * 16 + l15) * 32 + quad * 8);
#pragma unroll
    for (int mi = 0; mi < MI; ++mi)
#pragma unroll
      for (int ni = 0; ni < 4; ++ni)
        acc[mi][ni] = __builtin_amdgcn_mfma_f32_16x16x32_bf16(
            af[mi], bfr[ni], acc[mi][ni], 0, 0, 0);
    __syncthreads();
  }

  const int r0 = tile_m + wrow0 + quad * 4;
  const int c0 = tile_n + wn * 64 + l15;

  if (MODE == 0) {
    const bool isGate = (tile_n >= 3072);  // block-uniform (3072 % 128 == 0)
    const float* bp = isGate ? bias2 : bias;
    const int crel0 = isGate ? (c0 - 3072) : c0;
    const int nout = isGate ? 1024 : 3072;
    u16* outp = isGate ? C2 : (u16*)Cv;
#pragma unroll
    for (int mi = 0; mi < MI; ++mi) {
#pragma unroll
      for (int ni = 0; ni < 4; ++ni) {
        int col = crel0 + ni * 16;
        float bv = bp[col];
#pragma unroll
        for (int r = 0; r < 4; ++r) {
          float val = acc[mi][ni][r] + bv;
          if (isGate) val = 1.f / (1.f + __expf(-val));
          outp[(size_t)(r0 + mi * 16 + r) * nout + col] = f2bf(val);
        }
      }
    }
  } else {
#pragma unroll
    for (int mi = 0; mi < MI; ++mi) {
#pragma unroll
      for (int ni = 0; ni < 4; ++ni) {
        int col = c0 + ni * 16;
        float bv = bias[col];
#pragma unroll
        for (int r = 0; r < 4; ++r) {
          float val = acc[mi][ni][r] + bv;
          ((float*)Cv)[(size_t)(r0 + mi * 16 + r) * Nout + col] = val;
        }
      }
    }
  }
}

// ---------------- MFMA attention ----------------
// Block = (head, 64 queries), 4 waves x 16 queries. Per wave:
// 14 key-groups of 16 rows: g0..2 dense (bases n0-32,n0-16,n0) cover o=0..32;
// g3..13 sparse offsets (diagonal-only, off-diag masked to exp(-inf)=0).
__global__ __launch_bounds__(256) void attn_mfma_kernel(
    const u16* __restrict__ qkv, const float* __restrict__ pos_bias,
    const u16* __restrict__ gate, u16* __restrict__ a2) {
  __shared__ __align__(16) u16 Pl[4][16][232];
  __shared__ float pbs[NOFF];
  const int tid = threadIdx.x;
  const int lane = tid & 63;
  const int w = tid >> 6;
  const int h = blockIdx.y;
  const int n0 = blockIdx.x * 64 + w * 16;
  const int quad = lane >> 4;
  const int l15 = lane & 15;

  if (tid < NOFF) pbs[tid] = pos_bias[tid * NHEAD + h];

  const int soffs[11] = {48, 64, 96, 128, 192, 256, 384, 512, 768, 1024, 1536};
  int gbase[14];
  gbase[0] = n0 - 32; gbase[1] = n0 - 16; gbase[2] = n0;
#pragma unroll
  for (int g = 0; g < 11; ++g) gbase[3 + g] = n0 - soffs[g];

  const u16* qbase = qkv + (size_t)(n0 + l15) * 3072 + h * 64 + quad * 8;
  bf16x8 aq0 = *(const bf16x8*)(qbase);
  bf16x8 aq1 = *(const bf16x8*)(qbase + 32);

  // QK^T
  f32x4 s[14];
  const f32x4 zero = {0.f, 0.f, 0.f, 0.f};
#pragma unroll
  for (int g = 0; g < 14; ++g) {
    s[g] = zero;
    if (gbase[g] + 15 < 0) continue;
    int row = gbase[g] + l15;
    int rc = row < 0 ? 0 : row;
    const u16* kb = qkv + 1024 + (size_t)rc * 3072 + h * 64 + quad * 8;
    bf16x8 bk0 = *(const bf16x8*)(kb);
    bf16x8 bk1 = *(const bf16x8*)(kb + 32);
    s[g] = __builtin_amdgcn_mfma_f32_16x16x32_bf16(aq0, bk0, s[g], 0, 0, 0);
    s[g] = __builtin_amdgcn_mfma_f32_16x16x32_bf16(aq1, bk1, s[g], 0, 0, 0);
  }
  __syncthreads();  // pbs ready

  // scale + bias + mask
#pragma unroll
  for (int g = 0; g < 14; ++g) {
    int key = gbase[g] + l15;
#pragma unroll
    for (int r = 0; r < 4; ++r) {
      int q = n0 + quad * 4 + r;
      int o = q - key;
      bool valid; int bidx;
      if (g < 3) {
        valid = (o >= 0) & (o <= 32) & (key >= 0);
        bidx = o < 0 ? 0 : (o > 32 ? 32 : o);
      } else {
        valid = (key >= 0) & (o == soffs[g - 3]);
        bidx = g + 30;
      }
      float val = s[g][r] * 0.125f + pbs[bidx];
      s[g][r] = valid ? val : -INFINITY;
    }
  }

  // softmax over 224-wide rows
  float rl[4];
#pragma unroll
  for (int r = 0; r < 4; ++r) {
    float mx = s[0][r];
#pragma unroll
    for (int g = 1; g < 14; ++g) mx = fmaxf(mx, s[g][r]);
    mx = fmaxf(mx, __shfl_xor(mx, 1, 64));
    mx = fmaxf(mx, __shfl_xor(mx, 2, 64));
    mx = fmaxf(mx, __shfl_xor(mx, 4, 64));
    mx = fmaxf(mx, __shfl_xor(mx, 8, 64));
    float sum = 0.f;
#pragma unroll
    for (int g = 0; g < 14; ++g) {
      float p = __expf(s[g][r] - mx);
      s[g][r] = p;
      sum += p;
    }
    sum += __shfl_xor(sum, 1, 64);
    sum += __shfl_xor(sum, 2, 64);
    sum += __shfl_xor(sum, 4, 64);
    sum += __shfl_xor(sum, 8, 64);
    rl[r] = 1.0f / sum;
  }

  // P -> LDS (C-layout write, A-layout read)
#pragma unroll
  for (int g = 0; g < 14; ++g)
#pragma unroll
    for (int r = 0; r < 4; ++r)
      Pl[w][quad * 4 + r][g * 16 + l15] = f2bf(s[g][r]);
  __syncthreads();

  // PV
  f32x4 ov[4];
#pragma unroll
  for (int ni = 0; ni < 4; ++ni) ov[ni] = zero;
  const u16* vb = qkv + 2048 + h * 64;
#pragma unroll
  for (int kc = 0; kc < 7; ++kc) {
    if (gbase[2 * kc] + 15 < 0 && gbase[2 * kc + 1] + 15 < 0) continue;
    bf16x8 ap = *(const bf16x8*)(&Pl[w][l15][kc * 32 + quad * 8]);
    int g = kc * 2 + (quad >> 1);
    int keyg = gbase[g] + (quad & 1) * 8;
    const u16* rp[8];
#pragma unroll
    for (int j = 0; j < 8; ++j) {
      int row = keyg + j;
      rp[j] = vb + (size_t)(row < 0 ? 0 : row) * 3072;
    }
#pragma unroll
    for (int ni = 0; ni < 4; ++ni) {
      bf16x8 bv;
#pragma unroll
      for (int j = 0; j < 8; ++j) bv[j] = (short)rp[j][ni * 16 + l15];
      ov[ni] = __builtin_amdgcn_mfma_f32_16x16x32_bf16(ap, bv, ov[ni], 0, 0, 0);
    }
  }

  // epilogue: normalize, gate, store bf16
#pragma unroll
  for (int ni = 0; ni < 4; ++ni) {
#pragma unroll
    for (int r = 0; r < 4; ++r) {
      int q = n0 + quad * 4 + r;
      int col = h * 64 + ni * 16 + l15;
      float o = ov[ni][r] * rl[r];
      float g = bf2f(gate[(size_t)q * DMODEL + col]);
      a2[(size_t)q * DMODEL + col] = f2bf(o * g);
    }
  }
}

extern "C" void kernel_launch(void* const* d_in, const int* in_sizes, int n_in,
                              void* d_out, int out_size, void* d_ws,
                              size_t ws_size, hipStream_t stream) {
  (void)in_sizes; (void)n_in; (void)out_size; (void)ws_size;
  const float* x = (const float*)d_in[0];
  const float* Wqkv = (const float*)d_in[1];
  const float* bqkv = (const float*)d_in[2];
  const float* Wout = (const float*)d_in[3];
  const float* bout = (const float*)d_in[4];
  const float* Wgate = (const float*)d_in[5];
  const float* bgate = (const float*)d_in[6];
  const float* pos_bias = (const float*)d_in[7];
  float* out = (float*)d_out;

  char* ws = (char*)d_ws;
  u16* xb    = (u16*)(ws);                    // [2048,1024]  4 MB
  u16* Wcat  = (u16*)(ws + (4u << 20));       // [4096,1024]  8 MB (Wqkv|Wgate)
  u16* Woutb = (u16*)(ws + (12u << 20));      // [1024,1024]  2 MB
  u16* qkvb  = (u16*)(ws + (14u << 20));      // [2048,3072] 12 MB
  u16* gate  = (u16*)(ws + (26u << 20));      // [2048,1024]  4 MB bf16
  u16* a2    = (u16*)(ws + (30u << 20));      // [2048,1024]  4 MB

  cvt_all_kernel<<<7168, 256, 0, stream>>>(
      x, Wqkv, Wgate, Wout, xb, Wcat, Wcat + 3072 * 1024, Woutb);

  // [qkv | gate] = x @ [Wqkv;Wgate]^T, fused epilogue (bias / bias+sigmoid)
  gemm_bt<0, 128><<<dim3(32, 16), 256, 0, stream>>>(
      xb, Wcat, bqkv, qkvb, gate, bgate, 2048, 4096, 1024);
  // attention + gating -> a2 bf16 [2048, 1024]
  attn_mfma_kernel<<<dim3(32, 16), 256, 0, stream>>>(qkvb, pos_bias, gate, a2);
  // out = a2 @ Wout^T + bout -> fp32 [2048, 1024]
  gemm_bt<2, 64><<<dim3(16, 16), 256, 0, stream>>>(
      a2, Woutb, bout, out, nullptr, nullptr, 2048, 1024, 1024);
}

// Round 4
// 157.293 us; speedup vs baseline: 1.8451x; 1.0006x over previous
//
#include <hip/hip_runtime.h>
#include <cstdint>

typedef unsigned short u16;

#define NTOK 2048
#define DMODEL 1024
#define NHEAD 16
#define NOFF 44

typedef __attribute__((ext_vector_type(8))) short bf16x8;
typedef __attribute__((ext_vector_type(4))) float f32x4;

__device__ __forceinline__ u16 f2bf(float f) {
  uint32_t u = __builtin_bit_cast(uint32_t, f);
  u = (u + 0x7FFFu + ((u >> 16) & 1u)) >> 16;
  return (u16)u;
}
__device__ __forceinline__ float bf2f(u16 u) {
  return __builtin_bit_cast(float, ((uint32_t)u) << 16);
}

// ---------------- merged fp32 -> bf16 convert ----------------
__global__ __launch_bounds__(256) void cvt_all_kernel(
    const float* __restrict__ x, const float* __restrict__ wq,
    const float* __restrict__ wg, const float* __restrict__ wo,
    u16* __restrict__ xb, u16* __restrict__ wqb,
    u16* __restrict__ wgb, u16* __restrict__ wob) {
  int i = blockIdx.x * 256 + threadIdx.x;
  const float* in; u16* out; int off;
  if (i < 524288) { in = x; out = xb; off = 0; }
  else if (i < 524288 + 786432) { in = wq; out = wqb; off = 524288; }
  else if (i < 524288 + 786432 + 262144) { in = wg; out = wgb; off = 524288 + 786432; }
  else { in = wo; out = wob; off = 524288 + 786432 + 262144; }
  int j = i - off;
  float4 f = reinterpret_cast<const float4*>(in)[j];
  ushort4 o;
  o.x = f2bf(f.x); o.y = f2bf(f.y); o.z = f2bf(f.z); o.w = f2bf(f.w);
  reinterpret_cast<ushort4*>(out)[j] = o;
}

// ---------------- async global->LDS 16B ----------------
__device__ __forceinline__ void async16(const void* g, void* l) {
  __builtin_amdgcn_global_load_lds(
      (const __attribute__((address_space(1))) void*)g,
      (__attribute__((address_space(3))) void*)l,
      16, 0, 0);
}

// ---------------- bf16 MFMA GEMM: C = A @ B^T + bias ----------------
// BN=128: 128x128 tile, 4 waves 2x2, each 64x64 (acc 4x4)
// BN=64 : 128x64  tile, 4 waves 4x1, each 32x64 (acc 2x4)
// MODE 0: fused qkv+gate — cols [0,3072) -> bf16 qkv (+bias); V region
//         (cols [2048,3072)) ALSO written transposed to Vt[dim][key];
//         cols [3072,4096) -> bf16 sigmoid gate (+bias2). Block-uniform.
// MODE 2: fp32 out (+bias)
template <int MODE, int BN>
__global__ __launch_bounds__(256) void gemm_bt(
    const u16* __restrict__ A, const u16* __restrict__ B,
    const float* __restrict__ bias, void* __restrict__ Cv,
    u16* __restrict__ C2, const float* __restrict__ bias2,
    u16* __restrict__ Vt, int M, int Nout, int K) {
  constexpr int MI = (BN == 128) ? 4 : 2;
  __shared__ __align__(16) u16 As[128 * 32];
  __shared__ __align__(16) u16 Bs[BN * 32];
  const int tid = threadIdx.x;
  const int lane = tid & 63;
  const int w = tid >> 6;
  const int wm = (BN == 128) ? (w >> 1) : w;
  const int wn = (BN == 128) ? (w & 1) : 0;
  const int wrow0 = wm * (MI * 16);
  const int tile_m = blockIdx.y * 128;
  const int tile_n = blockIdx.x * BN;
  const int l15 = lane & 15;
  const int quad = lane >> 4;

  f32x4 acc[MI][4];
  const f32x4 zero = {0.f, 0.f, 0.f, 0.f};
#pragma unroll
  for (int mi = 0; mi < MI; ++mi)
#pragma unroll
    for (int ni = 0; ni < 4; ++ni) acc[mi][ni] = zero;

  const int rowInChunk = lane >> 2;
  const int colChunk = (lane & 3) * 8;

  for (int k0 = 0; k0 < K; k0 += 32) {
#pragma unroll
    for (int j = 0; j < 2; ++j) {
      int r = w * 32 + j * 16 + rowInChunk;
      async16(A + (size_t)(tile_m + r) * K + k0 + colChunk, As + r * 32 + colChunk);
    }
    if constexpr (BN == 128) {
#pragma unroll
      for (int j = 0; j < 2; ++j) {
        int r = w * 32 + j * 16 + rowInChunk;
        async16(B + (size_t)(tile_n + r) * K + k0 + colChunk, Bs + r * 32 + colChunk);
      }
    } else {
      int r = tid >> 2;
      int cc = (tid & 3) * 8;
      async16(B + (size_t)(tile_n + r) * K + k0 + cc, Bs + r * 32 + cc);
    }
    __syncthreads();

    bf16x8 af[MI], bfr[4];
#pragma unroll
    for (int mi = 0; mi < MI; ++mi)
      af[mi] = *(const bf16x8*)(As + (wrow0 + mi * 16 + l15) * 32 + quad * 8);
#pragma unroll
    for (int ni = 0; ni < 4; ++ni)
      bfr[ni] = *(const bf16x8*)(Bs + (wn * 64 + ni * 16 + l15) * 32 + quad * 8);
#pragma unroll
    for (int mi = 0; mi < MI; ++mi)
#pragma unroll
      for (int ni = 0; ni < 4; ++ni)
        acc[mi][ni] = __builtin_amdgcn_mfma_f32_16x16x32_bf16(
            af[mi], bfr[ni], acc[mi][ni], 0, 0, 0);
    __syncthreads();
  }

  const int r0 = tile_m + wrow0 + quad * 4;
  const int c0 = tile_n + wn * 64 + l15;

  if (MODE == 0) {
    const bool isGate = (tile_n >= 3072);  // block-uniform (3072 % 128 == 0)
    const bool isV = (tile_n >= 2048) && (tile_n < 3072);
    const float* bp = isGate ? bias2 : bias;
    const int crel0 = isGate ? (c0 - 3072) : c0;
    const int nout = isGate ? 1024 : 3072;
    u16* outp = isGate ? C2 : (u16*)Cv;
#pragma unroll
    for (int mi = 0; mi < MI; ++mi) {
#pragma unroll
      for (int ni = 0; ni < 4; ++ni) {
        int col = crel0 + ni * 16;
        float bv = bp[col];
        u16 tmp[4];
#pragma unroll
        for (int r = 0; r < 4; ++r) {
          float val = acc[mi][ni][r] + bv;
          if (isGate) val = 1.f / (1.f + __expf(-val));
          tmp[r] = f2bf(val);
          outp[(size_t)(r0 + mi * 16 + r) * nout + col] = tmp[r];
        }
        if (isV) {
          // transpose side-write: Vt[dim][key], 4 consecutive keys packed
          uint2 pk;
          pk.x = (uint32_t)tmp[0] | ((uint32_t)tmp[1] << 16);
          pk.y = (uint32_t)tmp[2] | ((uint32_t)tmp[3] << 16);
          *(uint2*)(Vt + (size_t)(col - 2048) * NTOK + (r0 + mi * 16)) = pk;
        }
      }
    }
  } else {
#pragma unroll
    for (int mi = 0; mi < MI; ++mi) {
#pragma unroll
      for (int ni = 0; ni < 4; ++ni) {
        int col = c0 + ni * 16;
        float bv = bias[col];
#pragma unroll
        for (int r = 0; r < 4; ++r) {
          float val = acc[mi][ni][r] + bv;
          ((float*)Cv)[(size_t)(r0 + mi * 16 + r) * Nout + col] = val;
        }
      }
    }
  }
}

// ---------------- MFMA attention ----------------
// Block = (head, 64 queries), 4 waves x 16 queries. Per wave:
// 14 key-groups of 16 rows: g0..2 dense (bases n0-32,n0-16,n0) cover o=0..32;
// g3..13 sparse offsets (diagonal-only, off-diag masked to exp(-inf)=0).
// PV B-frags are b128 loads from the pre-transposed Vt[dim][key] (all group
// bases are multiples of 16, so keyg is 8-aligned; negative bases clamp to 0
// and are annihilated by p=0).
__global__ __launch_bounds__(256) void attn_mfma_kernel(
    const u16* __restrict__ qkv, const u16* __restrict__ Vt,
    const float* __restrict__ pos_bias, const u16* __restrict__ gate,
    u16* __restrict__ a2) {
  __shared__ __align__(16) u16 Pl[4][16][232];
  __shared__ float pbs[NOFF];
  const int tid = threadIdx.x;
  const int lane = tid & 63;
  const int w = tid >> 6;
  const int h = blockIdx.y;
  const int n0 = blockIdx.x * 64 + w * 16;
  const int quad = lane >> 4;
  const int l15 = lane & 15;

  if (tid < NOFF) pbs[tid] = pos_bias[tid * NHEAD + h];

  const int soffs[11] = {48, 64, 96, 128, 192, 256, 384, 512, 768, 1024, 1536};
  int gbase[14];
  gbase[0] = n0 - 32; gbase[1] = n0 - 16; gbase[2] = n0;
#pragma unroll
  for (int g = 0; g < 11; ++g) gbase[3 + g] = n0 - soffs[g];

  const u16* qbase = qkv + (size_t)(n0 + l15) * 3072 + h * 64 + quad * 8;
  bf16x8 aq0 = *(const bf16x8*)(qbase);
  bf16x8 aq1 = *(const bf16x8*)(qbase + 32);

  // QK^T
  f32x4 s[14];
  const f32x4 zero = {0.f, 0.f, 0.f, 0.f};
#pragma unroll
  for (int g = 0; g < 14; ++g) {
    s[g] = zero;
    if (gbase[g] + 15 < 0) continue;
    int row = gbase[g] + l15;
    int rc = row < 0 ? 0 : row;
    const u16* kb = qkv + 1024 + (size_t)rc * 3072 + h * 64 + quad * 8;
    bf16x8 bk0 = *(const bf16x8*)(kb);
    bf16x8 bk1 = *(const bf16x8*)(kb + 32);
    s[g] = __builtin_amdgcn_mfma_f32_16x16x32_bf16(aq0, bk0, s[g], 0, 0, 0);
    s[g] = __builtin_amdgcn_mfma_f32_16x16x32_bf16(aq1, bk1, s[g], 0, 0, 0);
  }
  __syncthreads();  // pbs ready

  // scale + bias + mask
#pragma unroll
  for (int g = 0; g < 14; ++g) {
    int key = gbase[g] + l15;
#pragma unroll
    for (int r = 0; r < 4; ++r) {
      int q = n0 + quad * 4 + r;
      int o = q - key;
      bool valid; int bidx;
      if (g < 3) {
        valid = (o >= 0) & (o <= 32) & (key >= 0);
        bidx = o < 0 ? 0 : (o > 32 ? 32 : o);
      } else {
        valid = (key >= 0) & (o == soffs[g - 3]);
        bidx = g + 30;
      }
      float val = s[g][r] * 0.125f + pbs[bidx];
      s[g][r] = valid ? val : -INFINITY;
    }
  }

  // softmax over 224-wide rows
  float rl[4];
#pragma unroll
  for (int r = 0; r < 4; ++r) {
    float mx = s[0][r];
#pragma unroll
    for (int g = 1; g < 14; ++g) mx = fmaxf(mx, s[g][r]);
    mx = fmaxf(mx, __shfl_xor(mx, 1, 64));
    mx = fmaxf(mx, __shfl_xor(mx, 2, 64));
    mx = fmaxf(mx, __shfl_xor(mx, 4, 64));
    mx = fmaxf(mx, __shfl_xor(mx, 8, 64));
    float sum = 0.f;
#pragma unroll
    for (int g = 0; g < 14; ++g) {
      float p = __expf(s[g][r] - mx);
      s[g][r] = p;
      sum += p;
    }
    sum += __shfl_xor(sum, 1, 64);
    sum += __shfl_xor(sum, 2, 64);
    sum += __shfl_xor(sum, 4, 64);
    sum += __shfl_xor(sum, 8, 64);
    rl[r] = 1.0f / sum;
  }

  // P -> LDS (C-layout write, A-layout read)
#pragma unroll
  for (int g = 0; g < 14; ++g)
#pragma unroll
    for (int r = 0; r < 4; ++r)
      Pl[w][quad * 4 + r][g * 16 + l15] = f2bf(s[g][r]);
  __syncthreads();

  // PV: B-frags straight from Vt[dim][key] (b128, 8 consecutive keys)
  f32x4 ov[4];
#pragma unroll
  for (int ni = 0; ni < 4; ++ni) ov[ni] = zero;
  const u16* vtb = Vt + (size_t)(h * 64) * NTOK;
#pragma unroll
  for (int kc = 0; kc < 7; ++kc) {
    if (gbase[2 * kc] + 15 < 0 && gbase[2 * kc + 1] + 15 < 0) continue;
    bf16x8 ap = *(const bf16x8*)(&Pl[w][l15][kc * 32 + quad * 8]);
    int g = kc * 2 + (quad >> 1);
    int keyg = gbase[g] + (quad & 1) * 8;
    int kg = keyg < 0 ? 0 : keyg;  // clamped rows have p=0
#pragma unroll
    for (int ni = 0; ni < 4; ++ni) {
      bf16x8 bv = *(const bf16x8*)(vtb + (size_t)(ni * 16 + l15) * NTOK + kg);
      ov[ni] = __builtin_amdgcn_mfma_f32_16x16x32_bf16(ap, bv, ov[ni], 0, 0, 0);
    }
  }

  // epilogue: normalize, gate, store bf16
#pragma unroll
  for (int ni = 0; ni < 4; ++ni) {
#pragma unroll
    for (int r = 0; r < 4; ++r) {
      int q = n0 + quad * 4 + r;
      int col = h * 64 + ni * 16 + l15;
      float o = ov[ni][r] * rl[r];
      float g = bf2f(gate[(size_t)q * DMODEL + col]);
      a2[(size_t)q * DMODEL + col] = f2bf(o * g);
    }
  }
}

extern "C" void kernel_launch(void* const* d_in, const int* in_sizes, int n_in,
                              void* d_out, int out_size, void* d_ws,
                              size_t ws_size, hipStream_t stream) {
  (void)in_sizes; (void)n_in; (void)out_size; (void)ws_size;
  const float* x = (const float*)d_in[0];
  const float* Wqkv = (const float*)d_in[1];
  const float* bqkv = (const float*)d_in[2];
  const float* Wout = (const float*)d_in[3];
  const float* bout = (const float*)d_in[4];
  const float* Wgate = (const float*)d_in[5];
  const float* bgate = (const float*)d_in[6];
  const float* pos_bias = (const float*)d_in[7];
  float* out = (float*)d_out;

  char* ws = (char*)d_ws;
  u16* xb    = (u16*)(ws);                    // [2048,1024]  4 MB
  u16* Wcat  = (u16*)(ws + (4u << 20));       // [4096,1024]  8 MB (Wqkv|Wgate)
  u16* Woutb = (u16*)(ws + (12u << 20));      // [1024,1024]  2 MB
  u16* qkvb  = (u16*)(ws + (14u << 20));      // [2048,3072] 12 MB
  u16* gate  = (u16*)(ws + (26u << 20));      // [2048,1024]  4 MB bf16
  u16* a2    = (u16*)(ws + (30u << 20));      // [2048,1024]  4 MB
  u16* Vt    = (u16*)(ws + (34u << 20));      // [1024,2048]  4 MB (V^T)

  cvt_all_kernel<<<7168, 256, 0, stream>>>(
      x, Wqkv, Wgate, Wout, xb, Wcat, Wcat + 3072 * 1024, Woutb);

  // [qkv | gate] = x @ [Wqkv;Wgate]^T, fused epilogue (+V^T side-write)
  gemm_bt<0, 128><<<dim3(32, 16), 256, 0, stream>>>(
      xb, Wcat, bqkv, qkvb, gate, bgate, Vt, 2048, 4096, 1024);
  // attention + gating -> a2 bf16 [2048, 1024]
  attn_mfma_kernel<<<dim3(32, 16), 256, 0, stream>>>(qkvb, Vt, pos_bias, gate, a2);
  // out = a2 @ Wout^T + bout -> fp32 [2048, 1024]
  gemm_bt<2, 64><<<dim3(16, 16), 256, 0, stream>>>(
      a2, Woutb, bout, out, nullptr, nullptr, nullptr, 2048, 1024, 1024);
}